// Round 10
// baseline (192.479 us; speedup 1.0000x reference)
//
#include <hip/hip_runtime.h>

#define BSZ 2
#define SEQ 2048
#define CH  1024
#define NH  16
#define HD  64
#define LOG2E 1.4426950408889634f
#define MASKC (-14426.950408889634f)   /* -10000 * log2(e) */

typedef short  bf16x8 __attribute__((ext_vector_type(8)));
typedef short  bf16x4 __attribute__((ext_vector_type(4)));
typedef float  f32x4  __attribute__((ext_vector_type(4)));

__device__ __forceinline__ short f2bf(float f) {
    union { float f; unsigned u; } v; v.f = f;
    unsigned r = v.u + 0x7FFFu + ((v.u >> 16) & 1u);   // RNE
    return (short)(r >> 16);
}
// round-half-up bf16 (1 ulp tie-only difference vs RNE, 2 VALU ops)
__device__ __forceinline__ short f2bf_fast(float f) {
    union { float f; unsigned u; } v; v.f = f;
    return (short)((v.u + 0x8000u) >> 16);
}
__device__ __forceinline__ bf16x8 pack8(float4 a, float4 b) {
    bf16x8 o;
    o[0] = f2bf(a.x); o[1] = f2bf(a.y); o[2] = f2bf(a.z); o[3] = f2bf(a.w);
    o[4] = f2bf(b.x); o[5] = f2bf(b.y); o[6] = f2bf(b.z); o[7] = f2bf(b.w);
    return o;
}
// Single-instruction exp2 THROUGH THE COMPILER (TRANS-op result hazard needs
// a compiler-inserted wait state; bare inline asm broke correctness in R6).
__device__ __forceinline__ float exp2_hw(float x) {
#if __has_builtin(__builtin_amdgcn_exp2f)
    return __builtin_amdgcn_exp2f(x);
#else
    float r;
    asm volatile("v_exp_f32 %0, %1\n\ts_nop 1" : "=v"(r) : "v"(x));
    return r;
#endif
}

// 16x16x16 bf16 MFMA (K=16): C/D layout of a 16x16 MFMA equals this op's
// B-operand layout, which is what makes register-resident P^T possible.
#if __has_builtin(__builtin_amdgcn_mfma_f32_16x16x16bf16_1k)
__device__ __forceinline__ f32x4 mfma16x16x16(bf16x4 a, bf16x4 b, f32x4 c) {
    return __builtin_amdgcn_mfma_f32_16x16x16bf16_1k(a, b, c, 0, 0, 0);
}
#else
__device__ __forceinline__ f32x4 mfma16x16x16(bf16x4 a, bf16x4 b, f32x4 c) {
    f32x4 d;
    asm("v_mfma_f32_16x16x16_bf16 %0, %1, %2, %3"
        : "=v"(d) : "v"(a), "v"(b), "v"(c));
    return d;
}
#endif

// ---------------------------------------------------------------------------
// PREP kernel: W^T, V^T, mask->float.  (Q/K bf16 cast moved INTO proj staging
// — saves a 48 MB pass.)  Flat grid, block-range dispatch:
//   blocks [0, 512)     : Wq/Wk [k][n] -> wtq/wtk [n][k] bf16  (t<256 = Wq)
//   blocks [512, 1536)  : key [b][s][h*64+d] -> vtr [b*h][d][s] bf16
//   blocks [1536, 1552) : amask int -> mf float addend (*log2e)
// ---------------------------------------------------------------------------
__global__ __launch_bounds__(256) void prep(
    const float* __restrict__ key,
    const float* __restrict__ Wq, const float* __restrict__ Wk,
    const int*   __restrict__ am,
    short* __restrict__ wtq, short* __restrict__ wtk,
    short* __restrict__ vtr, float* __restrict__ mf)
{
    __shared__ float tile[64][65];
    const int bid = blockIdx.x;
    const int tid = threadIdx.x;

    if (bid >= 1536) {
        int i = (bid - 1536) * 256 + tid;
        mf[i] = (1.0f - (float)am[i]) * MASKC * (1.0f / 1.0f);
        return;
    }

    // ---- 64x64 tiled transpose + cast ----
    const float* s; short* d;
    int r0, c0, srs, drs;
    if (bid < 512) {
        int t = bid;                  // 0..511
        s   = (t < 256) ? Wq : Wk;
        d   = (t < 256) ? wtq : wtk;
        t  &= 255;
        r0  = (t >> 4) * 64;          // k
        c0  = (t & 15) * 64;          // n
        srs = CH; drs = CH;
    } else {
        int t = bid - 512;            // 0..1023
        int z = t >> 5;               // b*16+h, 0..31
        int sy = t & 31;              // s tile, 0..31
        s   = key + (long)(z >> 4) * SEQ * CH + (long)(z & 15) * HD;
        d   = vtr + (long)z * HD * SEQ;
        r0  = sy * 64;                // s
        c0  = 0;                      // d
        srs = CH; drs = SEQ;
    }

    const int r  = tid >> 2;          // 0..63
    const int c4 = (tid & 3) << 4;    // 0,16,32,48
    #pragma unroll
    for (int i = 0; i < 16; i += 4) {
        float4 v = *(const float4*)&s[(long)(r0 + r) * srs + c0 + c4 + i];
        tile[r][c4 + i + 0] = v.x;
        tile[r][c4 + i + 1] = v.y;
        tile[r][c4 + i + 2] = v.z;
        tile[r][c4 + i + 3] = v.w;
    }
    __syncthreads();
    bf16x8 o0, o1;
    #pragma unroll
    for (int i = 0; i < 8; i++) o0[i] = f2bf(tile[c4 + i][r]);
    #pragma unroll
    for (int i = 0; i < 8; i++) o1[i] = f2bf(tile[c4 + 8 + i][r]);
    *(bf16x8*)&d[(long)(c0 + r) * drs + r0 + c4 + 0] = o0;
    *(bf16x8*)&d[(long)(c0 + r) * drs + r0 + c4 + 8] = o1;
}

// ---------------------------------------------------------------------------
// Fused Q+K projection GEMM (blockIdx.z selects operand set).
// X is fp32 (cast to bf16 during LDS staging — removes the separate cast
// pass); Wt bf16 [n][k].  Y = bf16((X*W + bias)*scale).  128x128 tile,
// BK=64 (16 iters), 4 waves of 4x4 16x16x32 MFMAs x 2 k-halves.
// Double-buffered LDS, ONE barrier per iter.
// ---------------------------------------------------------------------------
__global__ __launch_bounds__(256, 2) void proj_mfma(
    const float* __restrict__ Xq, const float* __restrict__ Xk,
    const short* __restrict__ Wtq, const short* __restrict__ Wtk,
    const float* __restrict__ bq_, const float* __restrict__ bk_,
    short* __restrict__ Yq, short* __restrict__ Yk)
{
    __shared__ short At[2][128 * 72];
    __shared__ short Bt[2][128 * 72];
    const int zz = blockIdx.z;
    const float* X    = zz ? Xk  : Xq;
    const short* Wt   = zz ? Wtk : Wtq;
    const float* bias = zz ? bk_ : bq_;
    short*       Y    = zz ? Yk  : Yq;
    const float scale = zz ? 1.0f : (0.125f * LOG2E);  // fold 1/sqrt(D)*log2e into Q

    const int tid  = threadIdx.x;
    const int lane = tid & 63, w = tid >> 6;
    const int quad = lane >> 4, t16 = lane & 15;
    const int m0 = blockIdx.y * 128, n0 = blockIdx.x * 128;
    const int srow = tid >> 1;            // 0..127 staging row
    const int shalf = (tid & 1) * 32;     // 0 / 32 k-half (elements)

    f32x4 acc[4][4];
    #pragma unroll
    for (int i = 0; i < 4; i++)
        #pragma unroll
        for (int j = 0; j < 4; j++)
            acc[i][j] = (f32x4){0.f, 0.f, 0.f, 0.f};

    const int M0 = (w >> 1) * 64, N0 = (w & 1) * 64;
    const int NIT = CH / 64;

    float4 xr[8];
    bf16x8 br[4];
    // tile 0 -> regs -> buf0; tile 1 -> regs
    #pragma unroll
    for (int c = 0; c < 8; c++)
        xr[c] = *(const float4*)&X[(long)(m0 + srow) * CH + shalf + 4 * c];
    #pragma unroll
    for (int c = 0; c < 4; c++)
        br[c] = *(const bf16x8*)&Wt[(long)(n0 + srow) * CH + shalf + 8 * c];
    #pragma unroll
    for (int c = 0; c < 4; c++) {
        *(bf16x8*)&At[0][srow * 72 + shalf + 8 * c] = pack8(xr[2 * c], xr[2 * c + 1]);
        *(bf16x8*)&Bt[0][srow * 72 + shalf + 8 * c] = br[c];
    }
    #pragma unroll
    for (int c = 0; c < 8; c++)
        xr[c] = *(const float4*)&X[(long)(m0 + srow) * CH + 64 + shalf + 4 * c];
    #pragma unroll
    for (int c = 0; c < 4; c++)
        br[c] = *(const bf16x8*)&Wt[(long)(n0 + srow) * CH + 64 + shalf + 8 * c];
    __syncthreads();

    for (int it = 0; it < NIT; it++) {
        const int buf = it & 1;
        if (it + 1 < NIT) {
            #pragma unroll
            for (int c = 0; c < 4; c++) {
                *(bf16x8*)&At[buf ^ 1][srow * 72 + shalf + 8 * c] = pack8(xr[2 * c], xr[2 * c + 1]);
                *(bf16x8*)&Bt[buf ^ 1][srow * 72 + shalf + 8 * c] = br[c];
            }
            if (it + 2 < NIT) {
                const long ko = (long)(it + 2) * 64;
                #pragma unroll
                for (int c = 0; c < 8; c++)
                    xr[c] = *(const float4*)&X[(long)(m0 + srow) * CH + ko + shalf + 4 * c];
                #pragma unroll
                for (int c = 0; c < 4; c++)
                    br[c] = *(const bf16x8*)&Wt[(long)(n0 + srow) * CH + ko + shalf + 8 * c];
            }
        }

        #pragma unroll
        for (int kk = 0; kk < 2; kk++) {
            bf16x8 af[4], bw[4];
            #pragma unroll
            for (int im = 0; im < 4; im++)
                af[im] = *(bf16x8*)&At[buf][(M0 + 16 * im + t16) * 72 + kk * 32 + quad * 8];
            #pragma unroll
            for (int jn = 0; jn < 4; jn++)
                bw[jn] = *(bf16x8*)&Bt[buf][(N0 + 16 * jn + t16) * 72 + kk * 32 + quad * 8];
            #pragma unroll
            for (int im = 0; im < 4; im++)
                #pragma unroll
                for (int jn = 0; jn < 4; jn++)
                    acc[im][jn] = __builtin_amdgcn_mfma_f32_16x16x32_bf16(
                        af[im], bw[jn], acc[im][jn], 0, 0, 0);
        }
        __syncthreads();
    }

    #pragma unroll
    for (int jn = 0; jn < 4; jn++) {
        float bs = bias[n0 + N0 + 16 * jn + t16];
        #pragma unroll
        for (int im = 0; im < 4; im++)
            #pragma unroll
            for (int reg = 0; reg < 4; reg++) {
                float y = (acc[im][jn][reg] + bs) * scale;
                Y[(long)(m0 + M0 + 16 * im + 4 * quad + reg) * (NH * HD)
                  + n0 + N0 + 16 * jn + t16] = f2bf(y);
            }
    }
}

// ---------------------------------------------------------------------------
// Flash attention, TRANSPOSED-SCORE form, register-resident P.
//   S^T = K·Q^T ; S^T's C-layout == 16x16x16 B-operand layout, so P^T feeds
//   PV straight from registers.  Mask: PRECOMPUTED float addend (R7 path —
//   the R9 in-loop int4+cndmask version cost ~5 µs of exposed latency),
//   folded into the QK accumulator init.  exp2 via __builtin_amdgcn_exp2f.
//   Fixed-max softmax, l per-lane, quad-reduce at the end.
// K/V LDS double-buffered, ONE barrier per k-iter.  Block = 4 waves x 32 q
// = 128 q-rows; K-tile 64.  grid 16x16x2 = 512 (2 blocks/CU, 36.9 KB LDS).
// ---------------------------------------------------------------------------
__global__ __launch_bounds__(256, 2) void attn_mfma(
    const short* __restrict__ qp,    // [B*S][1024] bf16, pre-scaled 0.125*log2e
    const short* __restrict__ kp,    // [B*S][1024] bf16
    const short* __restrict__ vt,    // [B*H][64][S] bf16 (V transposed)
    const float* __restrict__ mf,    // [B][S] mask addend * log2e
    float* __restrict__ out)         // [B][S][H][D] fp32
{
    __shared__ short Kt[2][64 * 72];    // [key][d]
    __shared__ short Vt[2][64 * 72];    // [d][key]

    const int qt0 = blockIdx.x * 128;
    const int h   = blockIdx.y;
    const int b   = blockIdx.z;
    const int tid = threadIdx.x;
    const int lane = tid & 63, w = tid >> 6;
    const int quad = lane >> 4, t16 = lane & 15;

    // Q B-frags, loaded once: B[k = ds*32+quad*8+j][q = qm*16+t16]
    bf16x8 qf[2][2];
    #pragma unroll
    for (int qm = 0; qm < 2; qm++)
        #pragma unroll
        for (int ds = 0; ds < 2; ds++)
            qf[qm][ds] = *(const bf16x8*)&qp[
                (long)(b * SEQ + qt0 + w * 32 + qm * 16 + t16) * CH
                + h * HD + ds * 32 + quad * 8];

    f32x4 oa[4][2];                  // [dt][qm]: out^T [d=16dt+4quad+reg][q]
    float l_r[2];
    #pragma unroll
    for (int dt = 0; dt < 4; dt++)
        #pragma unroll
        for (int qm = 0; qm < 2; qm++)
            oa[dt][qm] = (f32x4){0.f, 0.f, 0.f, 0.f};
    l_r[0] = l_r[1] = 0.f;

    const int srow  = tid >> 2;           // 0..63
    const int scol  = (tid & 3) * 16;     // 0,16,32,48
    const long kbase = (long)(b * SEQ) * CH + h * HD;
    const long vbase = ((long)(b * NH + h) * HD) * SEQ;
    const int NIT = SEQ / 64;

    bf16x8 kr[2], vr[2];
    // tile 0 -> regs -> buf0; tile 1 -> regs
    #pragma unroll
    for (int c = 0; c < 2; c++) {
        kr[c] = *(const bf16x8*)&kp[kbase + (long)srow * CH + scol + 8 * c];
        vr[c] = *(const bf16x8*)&vt[vbase + (long)srow * SEQ + scol + 8 * c];
    }
    #pragma unroll
    for (int c = 0; c < 2; c++) {
        *(bf16x8*)&Kt[0][srow * 72 + scol + 8 * c] = kr[c];
        *(bf16x8*)&Vt[0][srow * 72 + scol + 8 * c] = vr[c];
    }
    #pragma unroll
    for (int c = 0; c < 2; c++) {
        kr[c] = *(const bf16x8*)&kp[kbase + (long)(64 + srow) * CH + scol + 8 * c];
        vr[c] = *(const bf16x8*)&vt[vbase + (long)srow * SEQ + 64 + scol + 8 * c];
    }
    __syncthreads();

    for (int it = 0; it < NIT; it++) {
        const int buf = it & 1;
        const int kt0 = it * 64;

        if (it + 1 < NIT) {
            #pragma unroll
            for (int c = 0; c < 2; c++) {
                *(bf16x8*)&Kt[buf ^ 1][srow * 72 + scol + 8 * c] = kr[c];
                *(bf16x8*)&Vt[buf ^ 1][srow * 72 + scol + 8 * c] = vr[c];
            }
            if (it + 2 < NIT) {
                const int kn = kt0 + 128;
                #pragma unroll
                for (int c = 0; c < 2; c++) {
                    kr[c] = *(const bf16x8*)&kp[kbase + (long)(kn + srow) * CH + scol + 8 * c];
                    vr[c] = *(const bf16x8*)&vt[vbase + (long)srow * SEQ + kn + scol + 8 * c];
                }
            }
        }

        // mask addend, per key row: regs 0..3 <- keys kt0+16jt+4quad+0..3
        float4 mv4[4];
        #pragma unroll
        for (int jt = 0; jt < 4; jt++)
            mv4[jt] = *(const float4*)&mf[b * SEQ + kt0 + jt * 16 + quad * 4];

        // ---- S^T = K * Q^T  (mask pre-loaded into the accumulator) ----
        f32x4 sa[2][4];
        #pragma unroll
        for (int qm = 0; qm < 2; qm++)
            #pragma unroll
            for (int jt = 0; jt < 4; jt++)
                sa[qm][jt] = (f32x4){mv4[jt].x, mv4[jt].y, mv4[jt].z, mv4[jt].w};
        #pragma unroll
        for (int ds = 0; ds < 2; ds++) {
            bf16x8 kb[4];   // A[m=key t16][k=d]
            #pragma unroll
            for (int jt = 0; jt < 4; jt++)
                kb[jt] = *(bf16x8*)&Kt[buf][(jt * 16 + t16) * 72 + ds * 32 + quad * 8];
            #pragma unroll
            for (int qm = 0; qm < 2; qm++)
                #pragma unroll
                for (int jt = 0; jt < 4; jt++)
                    sa[qm][jt] = __builtin_amdgcn_mfma_f32_16x16x32_bf16(
                        kb[jt], qf[qm][ds], sa[qm][jt], 0, 0, 0);
        }

        // ---- fixed-max softmax + pack to PV B-frags (own registers!) ----
        bf16x4 pb[2][4];
        #pragma unroll
        for (int qm = 0; qm < 2; qm++)
            #pragma unroll
            for (int jt = 0; jt < 4; jt++) {
                float p0 = exp2_hw(sa[qm][jt][0]);
                float p1 = exp2_hw(sa[qm][jt][1]);
                float p2 = exp2_hw(sa[qm][jt][2]);
                float p3 = exp2_hw(sa[qm][jt][3]);
                l_r[qm] += (p0 + p1) + (p2 + p3);
                bf16x4 pk;
                pk[0] = f2bf_fast(p0); pk[1] = f2bf_fast(p1);
                pk[2] = f2bf_fast(p2); pk[3] = f2bf_fast(p3);
                pb[qm][jt] = pk;
            }

        // ---- out^T += V^T * P^T  (16x16x16, A from LDS b64, B = pb regs) ----
        #pragma unroll
        for (int jt = 0; jt < 4; jt++) {
            bf16x4 va[4];   // A[m=d t16][k=key 4quad+j]
            #pragma unroll
            for (int dt = 0; dt < 4; dt++)
                va[dt] = *(bf16x4*)&Vt[buf][(dt * 16 + t16) * 72 + jt * 16 + quad * 4];
            #pragma unroll
            for (int dt = 0; dt < 4; dt++)
                #pragma unroll
                for (int qm = 0; qm < 2; qm++)
                    oa[dt][qm] = mfma16x16x16(va[dt], pb[qm][jt], oa[dt][qm]);
        }
        __syncthreads();
    }

    // ---- epilogue: quad-reduce l, normalize, store out^T -> out ----
    #pragma unroll
    for (int qm = 0; qm < 2; qm++) {
        float l = l_r[qm];
        l += __shfl_xor(l, 16, 64);
        l += __shfl_xor(l, 32, 64);
        float inv = 1.0f / l;
        int q = qt0 + w * 32 + qm * 16 + t16;
        #pragma unroll
        for (int dt = 0; dt < 4; dt++) {
            f32x4 o = oa[dt][qm];
            float4 st = {o[0] * inv, o[1] * inv, o[2] * inv, o[3] * inv};
            *(float4*)&out[((long)(b * SEQ + q) * NH + h) * HD + dt * 16 + quad * 4] = st;
        }
    }
}

extern "C" void kernel_launch(void* const* d_in, const int* in_sizes, int n_in,
                              void* d_out, int out_size, void* d_ws, size_t ws_size,
                              hipStream_t stream) {
    const float* query = (const float*)d_in[0];
    const float* key   = (const float*)d_in[1];
    const int*   amask = (const int*)d_in[2];
    const float* Wq    = (const float*)d_in[3];
    const float* bq    = (const float*)d_in[4];
    const float* Wk    = (const float*)d_in[5];
    const float* bk    = (const float*)d_in[6];
    float* out = (float*)d_out;

    char* ws = (char*)d_ws;
    const long MB = 1024 * 1024;
    short* qp  = (short*)(ws + 0 * MB);    // Q proj bf16 (8 MB)
    short* kp  = (short*)(ws + 8 * MB);    // K proj bf16 (8 MB)
    short* vtr = (short*)(ws + 16 * MB);   // V^T bf16 [B*H][64][2048] (8 MB)
    short* wtq = (short*)(ws + 24 * MB);   // Wq^T bf16 (2 MB)
    short* wtk = (short*)(ws + 26 * MB);   // Wk^T bf16 (2 MB)
    float* mfv = (float*)(ws + 28 * MB);   // mask addend [4096] f32

    prep<<<dim3(1552), 256, 0, stream>>>(key, Wq, Wk, amask, wtq, wtk, vtr, mfv);

    dim3 pgrid((NH * HD) / 128, (BSZ * SEQ) / 128, 2);   // 8 x 32 x 2 = 512
    proj_mfma<<<pgrid, 256, 0, stream>>>(query, key, wtq, wtk, bq, bk, qp, kp);

    dim3 agrid(SEQ / 128, NH, BSZ);                       // 16 x 16 x 2 = 512
    attn_mfma<<<agrid, 256, 0, stream>>>(qp, kp, vtr, mfv, out);
}